// Round 13
// baseline (327.272 us; speedup 1.0000x reference)
//
#include <hip/hip_runtime.h>
#include <math.h>

#define NROWS 4096
#define DDIM  1024

typedef __attribute__((ext_vector_type(8))) short short8;
typedef __attribute__((ext_vector_type(4))) float f32x4;

// ---------- bf16 helpers (manual RNE) ----------
__device__ __forceinline__ ushort f2bf(float v) {
  union { float f; uint32_t u; } c; c.f = v;
  uint32_t u = c.u;
  uint32_t lsb = (u >> 16) & 1u;
  u += 0x7fffu + lsb;
  return (ushort)(u >> 16);
}
__device__ __forceinline__ float bf2f(ushort h) {
  union { uint32_t u; float f; } c; c.u = ((uint32_t)h) << 16;
  return c.f;
}

// ---------- async global->LDS, 16B per lane ----------
__device__ __forceinline__ void gll16(const void* g, void* l) {
  __builtin_amdgcn_global_load_lds((const __attribute__((address_space(1))) void*)g,
                                   (__attribute__((address_space(3))) void*)l, 16, 0, 0);
}

// ---------- packed-fragment layouts ----------
// PLAIN: [R][C] bf16 as 16x32 tiles of 1KB (512 ushorts). tile T = (r>>4)*ldt+(c>>5);
//   intra ushort = ((c>>3)&3)*128 + (r&15)*8 + (c&7). Lane ln reads 16B at T*512+ln*8.
__device__ __forceinline__ size_t pidx(int r, int c, int ldt) {
  return ((size_t)((r >> 4) * ldt + (c >> 5))) * 512 +
         ((c >> 3) & 3) * 128 + (r & 15) * 8 + (c & 7);
}
// SPLIT-INTERLEAVED: hi fragment (512 ushorts) immediately followed by its lo
// fragment: tile T occupies 1024 ushorts; hi at T*1024+intra, lo at +512.
__device__ __forceinline__ size_t pidxs(int r, int c, int ldt) {
  return ((size_t)((r >> 4) * ldt + (c >> 5))) * 1024 +
         ((c >> 3) & 3) * 128 + (r & 15) * 8 + (c & 7);
}

// ---------- prep: split x + transpose/split 3 weights, packed outputs ----------
__global__ __launch_bounds__(256) void prep(const float* __restrict__ x,
                                            const float* __restrict__ wq,
                                            const float* __restrict__ wk,
                                            const float* __restrict__ wv,
                                            ushort* Xc,
                                            ushort* Wqc, ushort* Wkc, ushort* Wvh) {
  __shared__ float tl[32][33];
  const int b = blockIdx.x, t = threadIdx.x;
  if (b < 1024) {
    const f32x4* src = (const f32x4*)x;
#pragma unroll
    for (int r = 0; r < 4; ++r) {
      int i = b * 1024 + r * 256 + t;       // float4 index over [4096][256]
      int row = i >> 8;
      int c = (i & 255) << 2;               // 4-aligned column
      f32x4 v = __builtin_nontemporal_load(src + i);
      ushort4 h, l;
      h.x = f2bf(v.x); l.x = f2bf(v.x - bf2f(h.x));
      h.y = f2bf(v.y); l.y = f2bf(v.y - bf2f(h.y));
      h.z = f2bf(v.z); l.z = f2bf(v.z - bf2f(h.z));
      h.w = f2bf(v.w); l.w = f2bf(v.w - bf2f(h.w));
      size_t o = pidxs(row, c, DDIM / 32);  // (c&7)∈{0,4} -> 8B aligned
      *(ushort4*)(Xc + o) = h;
      *(ushort4*)(Xc + o + 512) = l;
    }
  } else {
    const int z = (b - 1024) >> 10;
    const int tile = (b - 1024) & 1023;
    const float* src = z == 0 ? wq : (z == 1 ? wk : wv);
    const int r0 = (tile >> 5) * 32;
    const int c0 = (tile & 31) * 32;
    const int tx = t & 31, ty = t >> 5;
    for (int i = ty; i < 32; i += 8)
      tl[i][tx] = __builtin_nontemporal_load(&src[(size_t)(r0 + i) * DDIM + c0 + tx]);
    __syncthreads();
    if (z == 2) {
      for (int i = ty; i < 32; i += 8) {
        float v = tl[tx][i];                // = W[r0+tx][c0+i]
        Wvh[pidx(c0 + i, r0 + tx, DDIM / 32)] = f2bf(v);
      }
    } else {
      ushort* d = z == 0 ? Wqc : Wkc;
      for (int i = ty; i < 32; i += 8) {
        float v = tl[tx][i];                // = W[r0+tx][c0+i]
        ushort h = f2bf(v);
        size_t o = pidxs(c0 + i, r0 + tx, DDIM / 32);  // W^T packed interleaved
        d[o] = h;
        d[o + 512] = f2bf(v - bf2f(h));
      }
    }
  }
}

// ---------- LDS-free, barrier-free direct packed-fragment GEMM core ----------
// Software-pipelined (distance-1 register double-buffer, static indices).
// KT = k-tiles to process; KTOT = total k-tiles in the buffer (frag-row stride).
// For split-K, pass A/B advanced by kt0*SA / kt0*SB and KT < KTOT.
template <int MI, bool SPLIT, int KT, int KTOT, int SA, int SB>
__device__ __forceinline__ void direct_gemm(const ushort* __restrict__ A,
                                            const ushort* __restrict__ B,
                                            int m0, int n0, f32x4 (*acc)[4]) {
  const int t = threadIdx.x;
  const int wv = t >> 6, ln = t & 63;
  const int arb = (wv >> 1) * (MI * 16), crb = (wv & 1) * 64;
  const int ra = (m0 + arb) >> 4;
  const int rb = (n0 + crb) >> 4;

  uint oA[MI], oB[4];
#pragma unroll
  for (int i = 0; i < MI; ++i) oA[i] = (uint)(ra + i) * (uint)(KTOT * SA) + (uint)ln * 8u;
#pragma unroll
  for (int j = 0; j < 4; ++j) oB[j] = (uint)(rb + j) * (uint)(KTOT * SB) + (uint)ln * 8u;

  short8 ah0[MI], al0[MI], bh0[4], bl0[4];
  short8 ah1[MI], al1[MI], bh1[4], bl1[4];

#define DG_LOAD(sidx, AH, AL, BH, BL)                                        \
  {                                                                          \
    uint sa_ = (uint)(sidx) * (uint)SA;                                      \
    uint sb_ = (uint)(sidx) * (uint)SB;                                      \
    _Pragma("unroll") for (int i_ = 0; i_ < MI; ++i_) {                      \
      const ushort* pa_ = A + oA[i_] + sa_;                                  \
      AH[i_] = *(const short8*)pa_;                                          \
      if constexpr (SPLIT) AL[i_] = *(const short8*)(pa_ + 512);             \
    }                                                                        \
    _Pragma("unroll") for (int j_ = 0; j_ < 4; ++j_) {                       \
      const ushort* pb_ = B + oB[j_] + sb_;                                  \
      BH[j_] = *(const short8*)pb_;                                          \
      if constexpr (SPLIT) BL[j_] = *(const short8*)(pb_ + 512);             \
    }                                                                        \
  }

#define DG_MFMA(AH, AL, BH, BL)                                              \
  {                                                                          \
    __builtin_amdgcn_s_setprio(1);                                           \
    _Pragma("unroll") for (int j_ = 0; j_ < 4; ++j_) {                       \
      _Pragma("unroll") for (int i_ = 0; i_ < MI; ++i_) {                    \
        acc[i_][j_] = __builtin_amdgcn_mfma_f32_16x16x32_bf16(               \
            AH[i_], BH[j_], acc[i_][j_], 0, 0, 0);                           \
        if constexpr (SPLIT) {                                               \
          acc[i_][j_] = __builtin_amdgcn_mfma_f32_16x16x32_bf16(             \
              AH[i_], BL[j_], acc[i_][j_], 0, 0, 0);                         \
          acc[i_][j_] = __builtin_amdgcn_mfma_f32_16x16x32_bf16(             \
              AL[i_], BH[j_], acc[i_][j_], 0, 0, 0);                         \
        }                                                                    \
      }                                                                      \
    }                                                                        \
    __builtin_amdgcn_s_setprio(0);                                           \
  }

  DG_LOAD(0, ah0, al0, bh0, bl0);
#pragma unroll 1
  for (int s = 0; s < KT - 2; s += 2) {
    DG_LOAD(s + 1, ah1, al1, bh1, bl1);
    DG_MFMA(ah0, al0, bh0, bl0);
    DG_LOAD(s + 2, ah0, al0, bh0, bl0);
    DG_MFMA(ah1, al1, bh1, bl1);
  }
  DG_LOAD(KT - 1, ah1, al1, bh1, bl1);
  DG_MFMA(ah0, al0, bh0, bl0);
  DG_MFMA(ah1, al1, bh1, bl1);

#undef DG_LOAD
#undef DG_MFMA
}

// ---------- fused QKV: direct-packed, no LDS, no barriers; XCD-chunked swizzle ----------
__global__ __launch_bounds__(256) void gemm_qkv(const ushort* __restrict__ Xc,
                                                const ushort* __restrict__ Wqc,
                                                const ushort* __restrict__ Wkc,
                                                const ushort* __restrict__ Wvh,
                                                ushort* Qc, ushort* Kc, ushort* Vt) {
  const int id = blockIdx.y * 24 + blockIdx.x;
  const int wg = (id & 7) * 96 + (id >> 3);
  const int bx = wg % 24, by = wg / 24;
  const int which = bx % 3;
  const int g = bx / 3;                      // 0..7 (d_out slice)
  const int t = threadIdx.x;
  const int wv = t >> 6, ln = t & 63;
  const int quad = ln >> 4, l16 = ln & 15;

  f32x4 acc[4][4];
#pragma unroll
  for (int i = 0; i < 4; ++i)
#pragma unroll
    for (int j = 0; j < 4; ++j) acc[i][j] = (f32x4){0.f, 0.f, 0.f, 0.f};

  if (which == 2) {
    const int m0 = g * 128;                  // d over 1024
    const int n0 = by * 128;                 // kv over 4096
    direct_gemm<4, false, 32, 32, 512, 1024>(Wvh, Xc, m0, n0, acc);
#pragma unroll
    for (int i = 0; i < 4; ++i)
#pragma unroll
      for (int j = 0; j < 4; ++j) {
        int kv = n0 + (wv & 1) * 64 + j * 16 + l16;
        int d = m0 + (wv >> 1) * 64 + i * 16 + quad * 4;
#pragma unroll
        for (int r2 = 0; r2 < 4; ++r2)
          Vt[pidx(d + r2, kv, NROWS / 32)] = f2bf(acc[i][j][r2]);
      }
  } else {
    const int n0 = g * 128;                  // d over 1024
    const int m0 = by * 128;                 // rows over 4096
    const ushort* Bc = which ? Wkc : Wqc;
    direct_gemm<4, true, 32, 32, 1024, 1024>(Xc, Bc, m0, n0, acc);
    const float scale = which ? 1.0f : 0.03125f;  // fold 1/sqrt(1024) into Q
    ushort* D = which ? Kc : Qc;
#pragma unroll
    for (int i = 0; i < 4; ++i)
#pragma unroll
      for (int j = 0; j < 4; ++j) {
        int col = n0 + (wv & 1) * 64 + j * 16 + l16;
        int rw = m0 + (wv >> 1) * 64 + i * 16 + quad * 4;
#pragma unroll
        for (int r2 = 0; r2 < 4; ++r2) {
          float v = acc[i][j][r2] * scale;
          ushort h = f2bf(v);
          size_t o = pidxs(rw + r2, col, DDIM / 32);
          D[o] = h;
          D[o + 512] = f2bf(v - bf2f(h));
        }
      }
  }
}

// ---------- S = Q*K^T (split): 256x256 tile, 8 waves, single-barrier LDS schedule ----
__global__ __launch_bounds__(512) void gemm_s(const ushort* __restrict__ Qc,
                                              const ushort* __restrict__ Kc,
                                              float* __restrict__ S) {
  __shared__ char smem[2][65536];
  const int bid = blockIdx.y * 16 + blockIdx.x;
  const int xcd = bid & 7, local = bid >> 3;   // 256 blocks = 1/CU
  const int m0 = ((xcd >> 1) * 4 + (local & 3)) * 256;
  const int n0 = ((xcd & 1) * 8 + (local >> 2)) * 256;
  const int t = threadIdx.x;
  const int w = t >> 6, ln = t & 63;
  const int wr = w >> 2, wc = w & 3;           // 2(M) x 4(N) wave grid
  const int quad = ln >> 4, l16 = ln & 15;

  const char* srcBase = (w < 4)
      ? (const char*)Qc + (size_t)((m0 >> 4) + w * 4) * 65536
      : (const char*)Kc + (size_t)((n0 >> 4) + (w - 4) * 4) * 65536;
  srcBase += ln * 16;
  char* ldsBase = (char*)smem + w * 8192 + ln * 16;

  f32x4 acc[8][4];
#pragma unroll
  for (int i = 0; i < 8; ++i)
#pragma unroll
    for (int j = 0; j < 4; ++j) acc[i][j] = (f32x4){0.f, 0.f, 0.f, 0.f};

#pragma unroll
  for (int u = 0; u < 8; ++u)
    gll16(srcBase + (u >> 1) * 65536 + (u & 1) * 1024, ldsBase + u * 1024);
  asm volatile("s_waitcnt vmcnt(0)" ::: "memory");
  __builtin_amdgcn_s_barrier();

  const char* aB = (char*)smem + (wr * 8) * 2048 + ln * 16;
  const char* bB = (char*)smem + 32768 + (wc * 4) * 2048 + ln * 16;

#pragma unroll 1
  for (int kt = 0; kt < 32; ++kt) {
    const int cb = (kt & 1) << 16;
    const int nb = ((kt + 1) & 1) << 16;
    const char* srcK = srcBase + (size_t)(kt + 1) * 2048;

    if (kt < 31) {
#pragma unroll
      for (int u = 0; u < 8; ++u)
        gll16(srcK + (u >> 1) * 65536 + (u & 1) * 1024, ldsBase + nb + u * 1024);
    }

    short8 bh[4], bl[4];
#pragma unroll
    for (int j = 0; j < 4; ++j) {
      bh[j] = *(const short8*)(bB + cb + j * 2048);
      bl[j] = *(const short8*)(bB + cb + j * 2048 + 1024);
    }

#pragma unroll
    for (int p = 0; p < 4; ++p) {
      short8 ah0 = *(const short8*)(aB + cb + (2 * p) * 2048);
      short8 al0 = *(const short8*)(aB + cb + (2 * p) * 2048 + 1024);
      short8 ah1 = *(const short8*)(aB + cb + (2 * p + 1) * 2048);
      short8 al1 = *(const short8*)(aB + cb + (2 * p + 1) * 2048 + 1024);
      __builtin_amdgcn_s_setprio(1);
#pragma unroll
      for (int j_ = 0; j_ < 4; ++j_) {
        acc[2 * p][j_] = __builtin_amdgcn_mfma_f32_16x16x32_bf16(ah0, bh[j_], acc[2 * p][j_], 0, 0, 0);
        acc[2 * p][j_] = __builtin_amdgcn_mfma_f32_16x16x32_bf16(ah0, bl[j_], acc[2 * p][j_], 0, 0, 0);
        acc[2 * p][j_] = __builtin_amdgcn_mfma_f32_16x16x32_bf16(al0, bh[j_], acc[2 * p][j_], 0, 0, 0);
        acc[2 * p + 1][j_] = __builtin_amdgcn_mfma_f32_16x16x32_bf16(ah1, bh[j_], acc[2 * p + 1][j_], 0, 0, 0);
        acc[2 * p + 1][j_] = __builtin_amdgcn_mfma_f32_16x16x32_bf16(ah1, bl[j_], acc[2 * p + 1][j_], 0, 0, 0);
        acc[2 * p + 1][j_] = __builtin_amdgcn_mfma_f32_16x16x32_bf16(al1, bh[j_], acc[2 * p + 1][j_], 0, 0, 0);
      }
      __builtin_amdgcn_s_setprio(0);
    }

    asm volatile("s_waitcnt vmcnt(0)" ::: "memory");
    __builtin_amdgcn_s_barrier();
  }

#pragma unroll
  for (int i = 0; i < 8; ++i)
#pragma unroll
    for (int j = 0; j < 4; ++j) {
      int col = n0 + wc * 64 + j * 16 + l16;
      int rw = m0 + wr * 128 + i * 16 + quad * 4;
#pragma unroll
      for (int r2 = 0; r2 < 4; ++r2)
        S[(size_t)(rw + r2) * NROWS + col] = acc[i][j][r2];
    }
}

// ---------- softmax: row of S (fp32) -> PACKED bf16 P (plain layout) ----------
__global__ __launch_bounds__(256) void softmax_pack(const float* __restrict__ S,
                                                    ushort* __restrict__ P) {
  const int row = blockIdx.x, t = threadIdx.x;
  const float* Sr = S + (size_t)row * NROWS;
  const f32x4* S4 = (const f32x4*)Sr;
  f32x4 v[4];
  float mx = -3.4e38f;
#pragma unroll
  for (int c = 0; c < 4; ++c) {
    v[c] = S4[c * 256 + t];
    mx = fmaxf(mx, fmaxf(fmaxf(v[c].x, v[c].y), fmaxf(v[c].z, v[c].w)));
  }
  __shared__ float red[4];
  for (int o = 32; o >= 1; o >>= 1) mx = fmaxf(mx, __shfl_xor(mx, o));
  int wv = t >> 6, ln = t & 63;
  if (ln == 0) red[wv] = mx;
  __syncthreads();
  mx = fmaxf(fmaxf(red[0], red[1]), fmaxf(red[2], red[3]));
  float s = 0.f;
#pragma unroll
  for (int c = 0; c < 4; ++c) {
    v[c].x = __expf(v[c].x - mx);
    v[c].y = __expf(v[c].y - mx);
    v[c].z = __expf(v[c].z - mx);
    v[c].w = __expf(v[c].w - mx);
    s += v[c].x + v[c].y + v[c].z + v[c].w;
  }
  for (int o = 32; o >= 1; o >>= 1) s += __shfl_xor(s, o);
  __syncthreads();
  if (ln == 0) red[wv] = s;
  __syncthreads();
  s = red[0] + red[1] + red[2] + red[3];
  float inv = 1.f / s;
#pragma unroll
  for (int c = 0; c < 4; ++c) {
    ushort4 h;
    h.x = f2bf(v[c].x * inv);
    h.y = f2bf(v[c].y * inv);
    h.z = f2bf(v[c].z * inv);
    h.w = f2bf(v[c].w * inv);
    int c0 = 1024 * c + 4 * t;            // 4 consecutive cols, 8B-aligned in packed space
    *(ushort4*)(P + pidx(row, c0, NROWS / 32)) = h;
  }
}

// ---------- Out = P*V, split-K x2: BM=128, grid (8,32,2) = 512 blocks -> 2/CU ----------
// Each z-half computes a partial over 64 k-tiles into its own fp32 buffer;
// reduce_add combines. Same MI=4 ratio as the r9 pv, 2x the TLP.
__global__ __launch_bounds__(256) void gemm_pv(const ushort* __restrict__ P,
                                               const ushort* __restrict__ Vt,
                                               float* __restrict__ Pa,
                                               float* __restrict__ Pb) {
  const int n0 = blockIdx.x * 128, m0 = blockIdx.y * 128;
  const int kb = blockIdx.z;                 // 0 or 1: k-tile range [kb*64, kb*64+64)
  const int t = threadIdx.x;
  const int wv = t >> 6, ln = t & 63;
  const int quad = ln >> 4, l16 = ln & 15;

  f32x4 acc[4][4];
#pragma unroll
  for (int i = 0; i < 4; ++i)
#pragma unroll
    for (int j = 0; j < 4; ++j) acc[i][j] = (f32x4){0.f, 0.f, 0.f, 0.f};

  const ushort* Pk = P + (size_t)kb * 64 * 512;
  const ushort* Vk = Vt + (size_t)kb * 64 * 512;
  direct_gemm<4, false, 64, 128, 512, 512>(Pk, Vk, m0, n0, acc);

  float* O = kb ? Pb : Pa;
#pragma unroll
  for (int i = 0; i < 4; ++i)
#pragma unroll
    for (int j = 0; j < 4; ++j) {
      int col = n0 + (wv & 1) * 64 + j * 16 + l16;
      int rw = m0 + (wv >> 1) * 64 + i * 16 + quad * 4;
#pragma unroll
      for (int r2 = 0; r2 < 4; ++r2)
        O[(size_t)(rw + r2) * DDIM + col] = acc[i][j][r2];
    }
}

// ---------- Out = Pa + Pb (vectorized) ----------
__global__ __launch_bounds__(256) void reduce_add(const float* __restrict__ a,
                                                  const float* __restrict__ b,
                                                  float* __restrict__ out) {
  size_t i = (size_t)blockIdx.x * 256 + threadIdx.x;   // f32x4 units
  const f32x4* a4 = (const f32x4*)a;
  const f32x4* b4 = (const f32x4*)b;
  f32x4* o4 = (f32x4*)out;
#pragma unroll
  for (int r = 0; r < 2; ++r, i += (size_t)2048 * 256)
    o4[i] = a4[i] + b4[i];
}

extern "C" void kernel_launch(void* const* d_in, const int* in_sizes, int n_in,
                              void* d_out, int out_size, void* d_ws, size_t ws_size,
                              hipStream_t stream) {
  const float* x  = (const float*)d_in[0];
  const float* wq = (const float*)d_in[1];
  const float* wk = (const float*)d_in[2];
  const float* wv = (const float*)d_in[3];
  char* ws = (char*)d_ws;
  const size_t MB = 1u << 20;

  // Workspace map (peak 104 MiB):
  ushort* Vt  = (ushort*)(ws + 0);        // 0-8    plain packed, alive through pv
  ushort* Qc  = (ushort*)(ws + 8 * MB);   // 8-24   interleaved split Q (dead after gemm_s)
  ushort* Kc  = (ushort*)(ws + 24 * MB);  // 24-40  interleaved split K (dead after gemm_s)
  ushort* Pp  = (ushort*)(ws + 8 * MB);   // 8-40   plain packed P (aliases dead Q/K)
  ushort* Xc  = (ushort*)(ws + 40 * MB);  // 40-56  interleaved split X (dead after qkv)
  ushort* Wqc = (ushort*)(ws + 56 * MB);  // 56-60  interleaved split W^T (dead after qkv)
  ushort* Wkc = (ushort*)(ws + 60 * MB);  // 60-64
  ushort* Wvh = (ushort*)(ws + 64 * MB);  // 64-66  plain W_v^T
  float*  S   = (float*)(ws + 40 * MB);   // 40-104 fp32 S (overwrites dead X/W)
  float*  Pa  = (float*)(ws + 40 * MB);   // 40-57  pv partial 0 (aliases dead S)
  float*  Pb  = (float*)(ws + 60 * MB);   // 60-77  pv partial 1
  float*  Out = (float*)d_out;

  prep<<<4096, 256, 0, stream>>>(x, wq, wk, wv, Xc, Wqc, Wkc, Wvh);
  gemm_qkv<<<dim3(24, 32), 256, 0, stream>>>(Xc, Wqc, Wkc, Wvh, Qc, Kc, Vt);
  gemm_s<<<dim3(16, 16), 512, 0, stream>>>(Qc, Kc, S);
  softmax_pack<<<NROWS, 256, 0, stream>>>(S, Pp);
  gemm_pv<<<dim3(8, 32, 2), 256, 0, stream>>>(Pp, Vt, Pa, Pb);
  reduce_add<<<2048, 256, 0, stream>>>(Pa, Pb, Out);
}

// Round 14
// 325.136 us; speedup vs baseline: 1.0066x; 1.0066x over previous
//
#include <hip/hip_runtime.h>
#include <math.h>

#define NROWS 4096
#define DDIM  1024

typedef __attribute__((ext_vector_type(8))) short short8;
typedef __attribute__((ext_vector_type(4))) float f32x4;
typedef __attribute__((ext_vector_type(16))) float f32x16;

// ---------- bf16 helpers (manual RNE) ----------
__device__ __forceinline__ ushort f2bf(float v) {
  union { float f; uint32_t u; } c; c.f = v;
  uint32_t u = c.u;
  uint32_t lsb = (u >> 16) & 1u;
  u += 0x7fffu + lsb;
  return (ushort)(u >> 16);
}
__device__ __forceinline__ float bf2f(ushort h) {
  union { uint32_t u; float f; } c; c.u = ((uint32_t)h) << 16;
  return c.f;
}

// ---------- async global->LDS, 16B per lane ----------
__device__ __forceinline__ void gll16(const void* g, void* l) {
  __builtin_amdgcn_global_load_lds((const __attribute__((address_space(1))) void*)g,
                                   (__attribute__((address_space(3))) void*)l, 16, 0, 0);
}

// ---------- packed-fragment layouts ----------
// PLAIN-16: [R][C] bf16 as 16x32 tiles of 1KB. tile T=(r>>4)*ldt+(c>>5);
//   intra = ((c>>3)&3)*128 + (r&15)*8 + (c&7). Lane ln reads 16B at T*512+ln*8.
//   (A-fragment for mfma 16x16x32: row=ln&15, k=(ln>>4)*8+e.)
__device__ __forceinline__ size_t pidx(int r, int c, int ldt) {
  return ((size_t)((r >> 4) * ldt + (c >> 5))) * 512 +
         ((c >> 3) & 3) * 128 + (r & 15) * 8 + (c & 7);
}
// SPLIT-16: hi fragment then its lo fragment (tile = 1024 ushorts).
__device__ __forceinline__ size_t pidxs(int r, int c, int ldt) {
  return ((size_t)((r >> 4) * ldt + (c >> 5))) * 1024 +
         ((c >> 3) & 3) * 128 + (r & 15) * 8 + (c & 7);
}
// SPLIT-32: 32x16 tiles of 1KB (hi) + 1KB (lo), for mfma 32x32x16 fragments:
//   lane ln reads 16B at ln*8 -> A[row=ln&31][k=(ln>>5)*8+e].
//   tile T = (r>>5)*ldt16 + (c>>4); intra = ((c>>3)&1)*256 + (r&31)*8 + (c&7).
__device__ __forceinline__ size_t pidx32s(int r, int c, int ldt16) {
  return ((size_t)((r >> 5) * ldt16 + (c >> 4))) * 1024 +
         ((c >> 3) & 1) * 256 + (r & 31) * 8 + (c & 7);
}

// ---------- prep: split x + transpose/split 3 weights, packed-16 outputs ----------
__global__ __launch_bounds__(256) void prep(const float* __restrict__ x,
                                            const float* __restrict__ wq,
                                            const float* __restrict__ wk,
                                            const float* __restrict__ wv,
                                            ushort* Xc,
                                            ushort* Wqc, ushort* Wkc, ushort* Wvh) {
  __shared__ float tl[32][33];
  const int b = blockIdx.x, t = threadIdx.x;
  if (b < 1024) {
    const f32x4* src = (const f32x4*)x;
#pragma unroll
    for (int r = 0; r < 4; ++r) {
      int i = b * 1024 + r * 256 + t;       // float4 index over [4096][256]
      int row = i >> 8;
      int c = (i & 255) << 2;               // 4-aligned column
      f32x4 v = __builtin_nontemporal_load(src + i);
      ushort4 h, l;
      h.x = f2bf(v.x); l.x = f2bf(v.x - bf2f(h.x));
      h.y = f2bf(v.y); l.y = f2bf(v.y - bf2f(h.y));
      h.z = f2bf(v.z); l.z = f2bf(v.z - bf2f(h.z));
      h.w = f2bf(v.w); l.w = f2bf(v.w - bf2f(h.w));
      size_t o = pidxs(row, c, DDIM / 32);  // (c&7)∈{0,4} -> 8B aligned
      *(ushort4*)(Xc + o) = h;
      *(ushort4*)(Xc + o + 512) = l;
    }
  } else {
    const int z = (b - 1024) >> 10;
    const int tile = (b - 1024) & 1023;
    const float* src = z == 0 ? wq : (z == 1 ? wk : wv);
    const int r0 = (tile >> 5) * 32;
    const int c0 = (tile & 31) * 32;
    const int tx = t & 31, ty = t >> 5;
    for (int i = ty; i < 32; i += 8)
      tl[i][tx] = __builtin_nontemporal_load(&src[(size_t)(r0 + i) * DDIM + c0 + tx]);
    __syncthreads();
    if (z == 2) {
      for (int i = ty; i < 32; i += 8) {
        float v = tl[tx][i];                // = W[r0+tx][c0+i]
        Wvh[pidx(c0 + i, r0 + tx, DDIM / 32)] = f2bf(v);
      }
    } else {
      ushort* d = z == 0 ? Wqc : Wkc;
      for (int i = ty; i < 32; i += 8) {
        float v = tl[tx][i];                // = W[r0+tx][c0+i]
        ushort h = f2bf(v);
        size_t o = pidxs(c0 + i, r0 + tx, DDIM / 32);  // W^T packed-16 interleaved
        d[o] = h;
        d[o + 512] = f2bf(v - bf2f(h));
      }
    }
  }
}

// ---------- LDS-free, barrier-free direct packed-16 GEMM core ----------
template <int MI, bool SPLIT, int KT, int KTOT, int SA, int SB>
__device__ __forceinline__ void direct_gemm(const ushort* __restrict__ A,
                                            const ushort* __restrict__ B,
                                            int m0, int n0, f32x4 (*acc)[4]) {
  const int t = threadIdx.x;
  const int wv = t >> 6, ln = t & 63;
  const int arb = (wv >> 1) * (MI * 16), crb = (wv & 1) * 64;
  const int ra = (m0 + arb) >> 4;
  const int rb = (n0 + crb) >> 4;

  uint oA[MI], oB[4];
#pragma unroll
  for (int i = 0; i < MI; ++i) oA[i] = (uint)(ra + i) * (uint)(KTOT * SA) + (uint)ln * 8u;
#pragma unroll
  for (int j = 0; j < 4; ++j) oB[j] = (uint)(rb + j) * (uint)(KTOT * SB) + (uint)ln * 8u;

  short8 ah0[MI], al0[MI], bh0[4], bl0[4];
  short8 ah1[MI], al1[MI], bh1[4], bl1[4];

#define DG_LOAD(sidx, AH, AL, BH, BL)                                        \
  {                                                                          \
    uint sa_ = (uint)(sidx) * (uint)SA;                                      \
    uint sb_ = (uint)(sidx) * (uint)SB;                                      \
    _Pragma("unroll") for (int i_ = 0; i_ < MI; ++i_) {                      \
      const ushort* pa_ = A + oA[i_] + sa_;                                  \
      AH[i_] = *(const short8*)pa_;                                          \
      if constexpr (SPLIT) AL[i_] = *(const short8*)(pa_ + 512);             \
    }                                                                        \
    _Pragma("unroll") for (int j_ = 0; j_ < 4; ++j_) {                       \
      const ushort* pb_ = B + oB[j_] + sb_;                                  \
      BH[j_] = *(const short8*)pb_;                                          \
      if constexpr (SPLIT) BL[j_] = *(const short8*)(pb_ + 512);             \
    }                                                                        \
  }

#define DG_MFMA(AH, AL, BH, BL)                                              \
  {                                                                          \
    __builtin_amdgcn_s_setprio(1);                                           \
    _Pragma("unroll") for (int j_ = 0; j_ < 4; ++j_) {                       \
      _Pragma("unroll") for (int i_ = 0; i_ < MI; ++i_) {                    \
        acc[i_][j_] = __builtin_amdgcn_mfma_f32_16x16x32_bf16(               \
            AH[i_], BH[j_], acc[i_][j_], 0, 0, 0);                           \
        if constexpr (SPLIT) {                                               \
          acc[i_][j_] = __builtin_amdgcn_mfma_f32_16x16x32_bf16(             \
              AH[i_], BL[j_], acc[i_][j_], 0, 0, 0);                         \
          acc[i_][j_] = __builtin_amdgcn_mfma_f32_16x16x32_bf16(             \
              AL[i_], BH[j_], acc[i_][j_], 0, 0, 0);                         \
        }                                                                    \
      }                                                                      \
    }                                                                        \
    __builtin_amdgcn_s_setprio(0);                                           \
  }

  DG_LOAD(0, ah0, al0, bh0, bl0);
#pragma unroll 1
  for (int s = 0; s < KT - 2; s += 2) {
    DG_LOAD(s + 1, ah1, al1, bh1, bl1);
    DG_MFMA(ah0, al0, bh0, bl0);
    DG_LOAD(s + 2, ah0, al0, bh0, bl0);
    DG_MFMA(ah1, al1, bh1, bl1);
  }
  DG_LOAD(KT - 1, ah1, al1, bh1, bl1);
  DG_MFMA(ah0, al0, bh0, bl0);
  DG_MFMA(ah1, al1, bh1, bl1);

#undef DG_LOAD
#undef DG_MFMA
}

// ---------- fused QKV: direct-packed; Q/K epilogues write packed-32 split ----------
__global__ __launch_bounds__(256) void gemm_qkv(const ushort* __restrict__ Xc,
                                                const ushort* __restrict__ Wqc,
                                                const ushort* __restrict__ Wkc,
                                                const ushort* __restrict__ Wvh,
                                                ushort* Qc, ushort* Kc, ushort* Vt) {
  const int id = blockIdx.y * 24 + blockIdx.x;
  const int wg = (id & 7) * 96 + (id >> 3);
  const int bx = wg % 24, by = wg / 24;
  const int which = bx % 3;
  const int g = bx / 3;                      // 0..7 (d_out slice)
  const int t = threadIdx.x;
  const int wv = t >> 6, ln = t & 63;
  const int quad = ln >> 4, l16 = ln & 15;

  f32x4 acc[4][4];
#pragma unroll
  for (int i = 0; i < 4; ++i)
#pragma unroll
    for (int j = 0; j < 4; ++j) acc[i][j] = (f32x4){0.f, 0.f, 0.f, 0.f};

  if (which == 2) {
    const int m0 = g * 128;                  // d over 1024
    const int n0 = by * 128;                 // kv over 4096
    direct_gemm<4, false, 32, 32, 512, 1024>(Wvh, Xc, m0, n0, acc);
#pragma unroll
    for (int i = 0; i < 4; ++i)
#pragma unroll
      for (int j = 0; j < 4; ++j) {
        int kv = n0 + (wv & 1) * 64 + j * 16 + l16;
        int d = m0 + (wv >> 1) * 64 + i * 16 + quad * 4;
#pragma unroll
        for (int r2 = 0; r2 < 4; ++r2)
          Vt[pidx(d + r2, kv, NROWS / 32)] = f2bf(acc[i][j][r2]);
      }
  } else {
    const int n0 = g * 128;                  // d over 1024
    const int m0 = by * 128;                 // rows over 4096
    const ushort* Bc = which ? Wkc : Wqc;
    direct_gemm<4, true, 32, 32, 1024, 1024>(Xc, Bc, m0, n0, acc);
    const float scale = which ? 1.0f : 0.03125f;  // fold 1/sqrt(1024) into Q
    ushort* D = which ? Kc : Qc;
#pragma unroll
    for (int i = 0; i < 4; ++i)
#pragma unroll
      for (int j = 0; j < 4; ++j) {
        int col = n0 + (wv & 1) * 64 + j * 16 + l16;
        int rw = m0 + (wv >> 1) * 64 + i * 16 + quad * 4;
#pragma unroll
        for (int r2 = 0; r2 < 4; ++r2) {
          float v = acc[i][j][r2] * scale;
          ushort h = f2bf(v);
          size_t o = pidx32s(rw + r2, col, DDIM / 16);   // packed-32 for gemm_s
          D[o] = h;
          D[o + 512] = f2bf(v - bf2f(h));
        }
      }
  }
}

// ---------- S = Q*K^T (split): 256x256 tile, 8 waves, single-barrier LDS schedule,
// ---------- 32x32x16 MFMA (15% faster pipe, 2x fewer instructions) ----------
// Packed-32 inputs: tile-row (32 rows) stride = 64 k-tiles * 2048B = 131072B.
// Per kt (32 k = 2 k-subtiles): stage next tile (8 gll16/wave), read B(2 tiles)
// + A(4 tiles) per ks, 48 MFMA32/wave, vmcnt(0) + ONE barrier.
__global__ __launch_bounds__(512) void gemm_s(const ushort* __restrict__ Qc,
                                              const ushort* __restrict__ Kc,
                                              float* __restrict__ S) {
  __shared__ char smem[2][65536];
  const int bid = blockIdx.y * 16 + blockIdx.x;
  const int xcd = bid & 7, local = bid >> 3;   // 256 blocks = 1/CU
  const int m0 = ((xcd >> 1) * 4 + (local & 3)) * 256;
  const int n0 = ((xcd & 1) * 8 + (local >> 2)) * 256;
  const int t = threadIdx.x;
  const int w = t >> 6, ln = t & 63;
  const int wr = w >> 2, wc = w & 3;           // 2(M) x 4(N) wave grid

  // staging: waves 0-3 stage A tile-rows 2w,2w+1; waves 4-7 stage B likewise.
  const char* srcBase = (w < 4)
      ? (const char*)Qc + (size_t)((m0 >> 5) + 2 * w) * 131072
      : (const char*)Kc + (size_t)((n0 >> 5) + 2 * (w - 4)) * 131072;
  srcBase += ln * 16;
  char* ldsBase = (char*)smem + (w < 4 ? 0 : 32768) + (w & 3) * 8192 + ln * 16;

  f32x16 acc[4][2];
#pragma unroll
  for (int i = 0; i < 4; ++i)
#pragma unroll
    for (int j = 0; j < 2; ++j) acc[i][j] = (f32x16)(0.f);

  // prologue: stage tile 0 into buf 0 (u = tr*4 + ks*2 + hl)
#pragma unroll
  for (int u = 0; u < 8; ++u)
    gll16(srcBase + (u >> 2) * 131072 + (u & 3) * 1024, ldsBase + u * 1024);
  asm volatile("s_waitcnt vmcnt(0)" ::: "memory");
  __builtin_amdgcn_s_barrier();

  // LDS per buffer: A tile-row tr(0-7): tr*4096 + ks*2048 + hl*1024; B at +32768.
  const char* aB = (char*)smem + (wr * 4) * 4096 + ln * 16;
  const char* bB = (char*)smem + 32768 + (wc * 2) * 4096 + ln * 16;

#pragma unroll 1
  for (int kt = 0; kt < 32; ++kt) {
    const int cb = (kt & 1) << 16;
    const int nb = ((kt + 1) & 1) << 16;
    const char* srcK = srcBase + (size_t)(kt + 1) * 4096;

    if (kt < 31) {
#pragma unroll
      for (int u = 0; u < 8; ++u)
        gll16(srcK + (u >> 2) * 131072 + (u & 3) * 1024, ldsBase + nb + u * 1024);
    }

#pragma unroll
    for (int ks = 0; ks < 2; ++ks) {
      short8 bh[2], bl[2];
#pragma unroll
      for (int j = 0; j < 2; ++j) {
        bh[j] = *(const short8*)(bB + cb + j * 4096 + ks * 2048);
        bl[j] = *(const short8*)(bB + cb + j * 4096 + ks * 2048 + 1024);
      }
      __builtin_amdgcn_s_setprio(1);
#pragma unroll
      for (int i = 0; i < 4; ++i) {
        short8 ah = *(const short8*)(aB + cb + i * 4096 + ks * 2048);
        short8 al = *(const short8*)(aB + cb + i * 4096 + ks * 2048 + 1024);
#pragma unroll
        for (int j = 0; j < 2; ++j) {
          acc[i][j] = __builtin_amdgcn_mfma_f32_32x32x16_bf16(ah, bh[j], acc[i][j], 0, 0, 0);
          acc[i][j] = __builtin_amdgcn_mfma_f32_32x32x16_bf16(ah, bl[j], acc[i][j], 0, 0, 0);
          acc[i][j] = __builtin_amdgcn_mfma_f32_32x32x16_bf16(al, bh[j], acc[i][j], 0, 0, 0);
        }
      }
      __builtin_amdgcn_s_setprio(0);
    }

    asm volatile("s_waitcnt vmcnt(0)" ::: "memory");
    __builtin_amdgcn_s_barrier();
  }

  // epilogue: 32x32 C/D layout: col=lane&31, row=(reg&3)+8*(reg>>2)+4*(lane>>5)
#pragma unroll
  for (int i = 0; i < 4; ++i)
#pragma unroll
    for (int j = 0; j < 2; ++j) {
      int colb = n0 + wc * 64 + j * 32 + (ln & 31);
      int rowb = m0 + wr * 128 + i * 32 + ((ln >> 5) << 2);
#pragma unroll
      for (int reg = 0; reg < 16; ++reg) {
        int row = rowb + (reg & 3) + ((reg >> 2) << 3);
        S[(size_t)row * NROWS + colb] = acc[i][j][reg];
      }
    }
}

// ---------- softmax: row of S (fp32) -> PACKED-16 bf16 P ----------
__global__ __launch_bounds__(256) void softmax_pack(const float* __restrict__ S,
                                                    ushort* __restrict__ P) {
  const int row = blockIdx.x, t = threadIdx.x;
  const float* Sr = S + (size_t)row * NROWS;
  const f32x4* S4 = (const f32x4*)Sr;
  f32x4 v[4];
  float mx = -3.4e38f;
#pragma unroll
  for (int c = 0; c < 4; ++c) {
    v[c] = S4[c * 256 + t];
    mx = fmaxf(mx, fmaxf(fmaxf(v[c].x, v[c].y), fmaxf(v[c].z, v[c].w)));
  }
  __shared__ float red[4];
  for (int o = 32; o >= 1; o >>= 1) mx = fmaxf(mx, __shfl_xor(mx, o));
  int wv = t >> 6, ln = t & 63;
  if (ln == 0) red[wv] = mx;
  __syncthreads();
  mx = fmaxf(fmaxf(red[0], red[1]), fmaxf(red[2], red[3]));
  float s = 0.f;
#pragma unroll
  for (int c = 0; c < 4; ++c) {
    v[c].x = __expf(v[c].x - mx);
    v[c].y = __expf(v[c].y - mx);
    v[c].z = __expf(v[c].z - mx);
    v[c].w = __expf(v[c].w - mx);
    s += v[c].x + v[c].y + v[c].z + v[c].w;
  }
  for (int o = 32; o >= 1; o >>= 1) s += __shfl_xor(s, o);
  __syncthreads();
  if (ln == 0) red[wv] = s;
  __syncthreads();
  s = red[0] + red[1] + red[2] + red[3];
  float inv = 1.f / s;
#pragma unroll
  for (int c = 0; c < 4; ++c) {
    ushort4 h;
    h.x = f2bf(v[c].x * inv);
    h.y = f2bf(v[c].y * inv);
    h.z = f2bf(v[c].z * inv);
    h.w = f2bf(v[c].w * inv);
    int c0 = 1024 * c + 4 * t;            // 4 consecutive cols, 8B-aligned in packed space
    *(ushort4*)(P + pidx(row, c0, NROWS / 32)) = h;
  }
}

// ---------- Out = P*V, LDS-free, barrier-free; BM=128 (r9 config) ----------
__global__ __launch_bounds__(256) void gemm_pv(const ushort* __restrict__ P,
                                               const ushort* __restrict__ Vt,
                                               float* __restrict__ Out) {
  const int n0 = blockIdx.x * 128, m0 = blockIdx.y * 128;
  const int t = threadIdx.x;
  const int wv = t >> 6, ln = t & 63;
  const int quad = ln >> 4, l16 = ln & 15;

  f32x4 acc[4][4];
#pragma unroll
  for (int i = 0; i < 4; ++i)
#pragma unroll
    for (int j = 0; j < 4; ++j) acc[i][j] = (f32x4){0.f, 0.f, 0.f, 0.f};

  direct_gemm<4, false, 128, 128, 512, 512>(P, Vt, m0, n0, acc);

#pragma unroll
  for (int i = 0; i < 4; ++i)
#pragma unroll
    for (int j = 0; j < 4; ++j) {
      int col = n0 + (wv & 1) * 64 + j * 16 + l16;
      int rw = m0 + (wv >> 1) * 64 + i * 16 + quad * 4;
#pragma unroll
      for (int r2 = 0; r2 < 4; ++r2)
        Out[(size_t)(rw + r2) * DDIM + col] = acc[i][j][r2];
    }
}

extern "C" void kernel_launch(void* const* d_in, const int* in_sizes, int n_in,
                              void* d_out, int out_size, void* d_ws, size_t ws_size,
                              hipStream_t stream) {
  const float* x  = (const float*)d_in[0];
  const float* wq = (const float*)d_in[1];
  const float* wk = (const float*)d_in[2];
  const float* wv = (const float*)d_in[3];
  char* ws = (char*)d_ws;
  const size_t MB = 1u << 20;

  // Workspace map (peak 104 MiB):
  ushort* Vt  = (ushort*)(ws + 0);        // 0-8    plain packed-16, alive through pv
  ushort* Qc  = (ushort*)(ws + 8 * MB);   // 8-24   packed-32 split Q (dead after gemm_s)
  ushort* Kc  = (ushort*)(ws + 24 * MB);  // 24-40  packed-32 split K (dead after gemm_s)
  ushort* Pp  = (ushort*)(ws + 8 * MB);   // 8-40   packed-16 P (aliases dead Q/K)
  ushort* Xc  = (ushort*)(ws + 40 * MB);  // 40-56  packed-16 split X (dead after qkv)
  ushort* Wqc = (ushort*)(ws + 56 * MB);  // 56-60  packed-16 split W^T (dead after qkv)
  ushort* Wkc = (ushort*)(ws + 60 * MB);  // 60-64
  ushort* Wvh = (ushort*)(ws + 64 * MB);  // 64-66  plain W_v^T
  float*  S   = (float*)(ws + 40 * MB);   // 40-104 fp32 S (overwrites dead X/W)
  float*  Out = (float*)d_out;

  prep<<<4096, 256, 0, stream>>>(x, wq, wk, wv, Xc, Wqc, Wkc, Wvh);
  gemm_qkv<<<dim3(24, 32), 256, 0, stream>>>(Xc, Wqc, Wkc, Wvh, Qc, Kc, Vt);
  gemm_s<<<dim3(16, 16), 512, 0, stream>>>(Qc, Kc, S);
  softmax_pack<<<NROWS, 256, 0, stream>>>(S, Pp);
  gemm_pv<<<dim3(8, 32), 256, 0, stream>>>(Pp, Vt, Out);
}

// Round 15
// 300.549 us; speedup vs baseline: 1.0889x; 1.0818x over previous
//
#include <hip/hip_runtime.h>
#include <math.h>

#define NROWS 4096
#define DDIM  1024

typedef __attribute__((ext_vector_type(8))) short short8;
typedef __attribute__((ext_vector_type(4))) float f32x4;

// ---------- bf16 helpers (manual RNE) ----------
__device__ __forceinline__ ushort f2bf(float v) {
  union { float f; uint32_t u; } c; c.f = v;
  uint32_t u = c.u;
  uint32_t lsb = (u >> 16) & 1u;
  u += 0x7fffu + lsb;
  return (ushort)(u >> 16);
}
__device__ __forceinline__ float bf2f(ushort h) {
  union { uint32_t u; float f; } c; c.u = ((uint32_t)h) << 16;
  return c.f;
}

// ---------- async global->LDS, 16B per lane ----------
__device__ __forceinline__ void gll16(const void* g, void* l) {
  __builtin_amdgcn_global_load_lds((const __attribute__((address_space(1))) void*)g,
                                   (__attribute__((address_space(3))) void*)l, 16, 0, 0);
}

// ---------- packed-fragment layouts ----------
// PLAIN-16: [R][C] bf16 as 16x32 tiles of 1KB (512 ushorts). tile T=(r>>4)*ldt+(c>>5);
//   intra = ((c>>3)&3)*128 + (r&15)*8 + (c&7). Lane ln reads 16B at T*512+ln*8.
__device__ __forceinline__ size_t pidx(int r, int c, int ldt) {
  return ((size_t)((r >> 4) * ldt + (c >> 5))) * 512 +
         ((c >> 3) & 3) * 128 + (r & 15) * 8 + (c & 7);
}
// SPLIT-16: hi fragment then its lo fragment (tile = 1024 ushorts; lo at +512).
__device__ __forceinline__ size_t pidxs(int r, int c, int ldt) {
  return ((size_t)((r >> 4) * ldt + (c >> 5))) * 1024 +
         ((c >> 3) & 3) * 128 + (r & 15) * 8 + (c & 7);
}

// ---------- prep: split x + transpose/split 3 weights, packed outputs ----------
__global__ __launch_bounds__(256) void prep(const float* __restrict__ x,
                                            const float* __restrict__ wq,
                                            const float* __restrict__ wk,
                                            const float* __restrict__ wv,
                                            ushort* Xc,
                                            ushort* Wqc, ushort* Wkc, ushort* Wvh) {
  __shared__ float tl[32][33];
  const int b = blockIdx.x, t = threadIdx.x;
  if (b < 1024) {
    const f32x4* src = (const f32x4*)x;
#pragma unroll
    for (int r = 0; r < 4; ++r) {
      int i = b * 1024 + r * 256 + t;       // float4 index over [4096][256]
      int row = i >> 8;
      int c = (i & 255) << 2;               // 4-aligned column
      f32x4 v = __builtin_nontemporal_load(src + i);
      ushort4 h, l;
      h.x = f2bf(v.x); l.x = f2bf(v.x - bf2f(h.x));
      h.y = f2bf(v.y); l.y = f2bf(v.y - bf2f(h.y));
      h.z = f2bf(v.z); l.z = f2bf(v.z - bf2f(h.z));
      h.w = f2bf(v.w); l.w = f2bf(v.w - bf2f(h.w));
      size_t o = pidxs(row, c, DDIM / 32);  // (c&7)∈{0,4} -> 8B aligned
      *(ushort4*)(Xc + o) = h;
      *(ushort4*)(Xc + o + 512) = l;
    }
  } else {
    const int z = (b - 1024) >> 10;
    const int tile = (b - 1024) & 1023;
    const float* src = z == 0 ? wq : (z == 1 ? wk : wv);
    const int r0 = (tile >> 5) * 32;
    const int c0 = (tile & 31) * 32;
    const int tx = t & 31, ty = t >> 5;
    for (int i = ty; i < 32; i += 8)
      tl[i][tx] = __builtin_nontemporal_load(&src[(size_t)(r0 + i) * DDIM + c0 + tx]);
    __syncthreads();
    if (z == 2) {
      for (int i = ty; i < 32; i += 8) {
        float v = tl[tx][i];                // = W[r0+tx][c0+i]
        Wvh[pidx(c0 + i, r0 + tx, DDIM / 32)] = f2bf(v);
      }
    } else {
      ushort* d = z == 0 ? Wqc : Wkc;
      for (int i = ty; i < 32; i += 8) {
        float v = tl[tx][i];                // = W[r0+tx][c0+i]
        ushort h = f2bf(v);
        size_t o = pidxs(c0 + i, r0 + tx, DDIM / 32);  // W^T packed-16 interleaved
        d[o] = h;
        d[o + 512] = f2bf(v - bf2f(h));
      }
    }
  }
}

// ---------- LDS-free, barrier-free direct packed-16 GEMM core (pv only) ----------
template <int MI, bool SPLIT, int KT, int KTOT, int SA, int SB>
__device__ __forceinline__ void direct_gemm(const ushort* __restrict__ A,
                                            const ushort* __restrict__ B,
                                            int m0, int n0, f32x4 (*acc)[4]) {
  const int t = threadIdx.x;
  const int wv = t >> 6, ln = t & 63;
  const int arb = (wv >> 1) * (MI * 16), crb = (wv & 1) * 64;
  const int ra = (m0 + arb) >> 4;
  const int rb = (n0 + crb) >> 4;

  uint oA[MI], oB[4];
#pragma unroll
  for (int i = 0; i < MI; ++i) oA[i] = (uint)(ra + i) * (uint)(KTOT * SA) + (uint)ln * 8u;
#pragma unroll
  for (int j = 0; j < 4; ++j) oB[j] = (uint)(rb + j) * (uint)(KTOT * SB) + (uint)ln * 8u;

  short8 ah0[MI], al0[MI], bh0[4], bl0[4];
  short8 ah1[MI], al1[MI], bh1[4], bl1[4];

#define DG_LOAD(sidx, AH, AL, BH, BL)                                        \
  {                                                                          \
    uint sa_ = (uint)(sidx) * (uint)SA;                                      \
    uint sb_ = (uint)(sidx) * (uint)SB;                                      \
    _Pragma("unroll") for (int i_ = 0; i_ < MI; ++i_) {                      \
      const ushort* pa_ = A + oA[i_] + sa_;                                  \
      AH[i_] = *(const short8*)pa_;                                          \
      if constexpr (SPLIT) AL[i_] = *(const short8*)(pa_ + 512);             \
    }                                                                        \
    _Pragma("unroll") for (int j_ = 0; j_ < 4; ++j_) {                       \
      const ushort* pb_ = B + oB[j_] + sb_;                                  \
      BH[j_] = *(const short8*)pb_;                                          \
      if constexpr (SPLIT) BL[j_] = *(const short8*)(pb_ + 512);             \
    }                                                                        \
  }

#define DG_MFMA(AH, AL, BH, BL)                                              \
  {                                                                          \
    __builtin_amdgcn_s_setprio(1);                                           \
    _Pragma("unroll") for (int j_ = 0; j_ < 4; ++j_) {                       \
      _Pragma("unroll") for (int i_ = 0; i_ < MI; ++i_) {                    \
        acc[i_][j_] = __builtin_amdgcn_mfma_f32_16x16x32_bf16(               \
            AH[i_], BH[j_], acc[i_][j_], 0, 0, 0);                           \
        if constexpr (SPLIT) {                                               \
          acc[i_][j_] = __builtin_amdgcn_mfma_f32_16x16x32_bf16(             \
              AH[i_], BL[j_], acc[i_][j_], 0, 0, 0);                         \
          acc[i_][j_] = __builtin_amdgcn_mfma_f32_16x16x32_bf16(             \
              AL[i_], BH[j_], acc[i_][j_], 0, 0, 0);                         \
        }                                                                    \
      }                                                                      \
    }                                                                        \
    __builtin_amdgcn_s_setprio(0);                                           \
  }

  DG_LOAD(0, ah0, al0, bh0, bl0);
#pragma unroll 1
  for (int s = 0; s < KT - 2; s += 2) {
    DG_LOAD(s + 1, ah1, al1, bh1, bl1);
    DG_MFMA(ah0, al0, bh0, bl0);
    DG_LOAD(s + 2, ah0, al0, bh0, bl0);
    DG_MFMA(ah1, al1, bh1, bl1);
  }
  DG_LOAD(KT - 1, ah1, al1, bh1, bl1);
  DG_MFMA(ah0, al0, bh0, bl0);
  DG_MFMA(ah1, al1, bh1, bl1);

#undef DG_LOAD
#undef DG_MFMA
}

// ---------- fused QKV: 128x128-tile LDS single-barrier schedule, 768 blocks ----------
// Blocks 0-255: Q (split, work 3). 256-511: K (split, work 3). 512-767: V (plain,
// work 1). Q+K fill 2 blocks/CU (512 resident); V backfills as slots free ->
// self-balancing. 4 waves (2x2 of 64x64). LDS 2x32KB double-buffered.
// Per-element summation order identical to direct core (kt asc; hh,hl,lh).
__global__ __launch_bounds__(256) void gemm_qkv(const ushort* __restrict__ Xc,
                                                const ushort* __restrict__ Wqc,
                                                const ushort* __restrict__ Wkc,
                                                const ushort* __restrict__ Wvh,
                                                ushort* Qc, ushort* Kc, ushort* Vt) {
  __shared__ char smem[2][32768];
  const int bid = blockIdx.x;
  const int which = bid >> 8;                // 0=Q, 1=K, 2=V
  const int local = bid & 255;
  const int xcd = local & 7, idx = local >> 3;
  const int t = threadIdx.x;
  const int w = t >> 6, ln = t & 63;
  const int wr = w >> 1, wc = w & 1;         // 2x2 wave grid, 64x64 each
  const int quad = ln >> 4, l16 = ln & 15;

  f32x4 acc[4][4];
#pragma unroll
  for (int i = 0; i < 4; ++i)
#pragma unroll
    for (int j = 0; j < 4; ++j) acc[i][j] = (f32x4){0.f, 0.f, 0.f, 0.f};

  if (which < 2) {
    // ---- Q/K: [m0..m0+127][n0..n0+127] = X(split) . W^T(split), K=1024 ----
    const int m0 = (xcd * 4 + (idx >> 3)) * 128;   // rows over 4096
    const int n0 = (idx & 7) * 128;                // d over 1024
    const ushort* Bc = which ? Wkc : Wqc;
    // staging: waves 0-1 stage A frag-pairs w*4..w*4+3 (8KB each); 2-3 stage B.
    const char* srcBase = (w < 2)
        ? (const char*)Xc + (size_t)((m0 >> 4) + (w & 1) * 4) * 65536
        : (const char*)Bc + (size_t)((n0 >> 4) + (w & 1) * 4) * 65536;
    srcBase += ln * 16;
    char* ldsBase = (char*)smem + (w < 2 ? 0 : 16384) + (w & 1) * 8192 + ln * 16;

    // prologue: stage tile 0 into buf 0 (u = fragrow*2 + half)
#pragma unroll
    for (int u = 0; u < 8; ++u)
      gll16(srcBase + (u >> 1) * 65536 + (u & 1) * 1024, ldsBase + u * 1024);
    asm volatile("s_waitcnt vmcnt(0)" ::: "memory");
    __builtin_amdgcn_s_barrier();

    const char* aB = (char*)smem + wr * 8192 + ln * 16;             // A frags wr*4+i
    const char* bB = (char*)smem + 16384 + wc * 8192 + ln * 16;     // B frags wc*4+j

#pragma unroll 1
    for (int kt = 0; kt < 32; ++kt) {
      const int cb = (kt & 1) << 15;
      const int nb = ((kt + 1) & 1) << 15;
      if (kt < 31) {
        const char* srcK = srcBase + (size_t)(kt + 1) * 2048;
#pragma unroll
        for (int u = 0; u < 8; ++u)
          gll16(srcK + (u >> 1) * 65536 + (u & 1) * 1024, ldsBase + nb + u * 1024);
      }

      short8 bh[4], bl[4];
#pragma unroll
      for (int j = 0; j < 4; ++j) {
        bh[j] = *(const short8*)(bB + cb + j * 2048);
        bl[j] = *(const short8*)(bB + cb + j * 2048 + 1024);
      }
      __builtin_amdgcn_s_setprio(1);
#pragma unroll
      for (int i = 0; i < 4; ++i) {
        short8 ah = *(const short8*)(aB + cb + i * 2048);
        short8 al = *(const short8*)(aB + cb + i * 2048 + 1024);
#pragma unroll
        for (int j = 0; j < 4; ++j) {
          acc[i][j] = __builtin_amdgcn_mfma_f32_16x16x32_bf16(ah, bh[j], acc[i][j], 0, 0, 0);
          acc[i][j] = __builtin_amdgcn_mfma_f32_16x16x32_bf16(ah, bl[j], acc[i][j], 0, 0, 0);
          acc[i][j] = __builtin_amdgcn_mfma_f32_16x16x32_bf16(al, bh[j], acc[i][j], 0, 0, 0);
        }
      }
      __builtin_amdgcn_s_setprio(0);

      asm volatile("s_waitcnt vmcnt(0)" ::: "memory");
      __builtin_amdgcn_s_barrier();
    }

    const float scale = which ? 1.0f : 0.03125f;   // fold 1/sqrt(1024) into Q
    ushort* D = which ? Kc : Qc;
#pragma unroll
    for (int i = 0; i < 4; ++i)
#pragma unroll
      for (int j = 0; j < 4; ++j) {
        int col = n0 + wc * 64 + j * 16 + l16;
        int rw = m0 + wr * 64 + i * 16 + quad * 4;
#pragma unroll
        for (int r2 = 0; r2 < 4; ++r2) {
          float v = acc[i][j][r2] * scale;
          ushort h = f2bf(v);
          size_t o = pidxs(rw + r2, col, DDIM / 32);
          D[o] = h;
          D[o + 512] = f2bf(v - bf2f(h));
        }
      }
  } else {
    // ---- V: Vt[d][kv] = WvT(plain) . X(hi only), K=1024 ----
    const int m0 = (idx & 7) * 128;                // d over 1024
    const int n0 = (xcd * 4 + (idx >> 3)) * 128;   // kv over 4096
    // staging: waves 0-1 stage A (Wvh plain) frags w*4+u; 2-3 stage B (Xc hi).
    const char* srcBase = (w < 2)
        ? (const char*)Wvh + (size_t)((m0 >> 4) + (w & 1) * 4) * 32768
        : (const char*)Xc + (size_t)((n0 >> 4) + (w & 1) * 4) * 65536;
    srcBase += ln * 16;
    char* ldsBase = (char*)smem + (w < 2 ? 0 : 8192) + (w & 1) * 4096 + ln * 16;
    const size_t srcStep = (w < 2) ? 1024 : 2048;  // per-kt byte step
    const size_t rowStr = (w < 2) ? 32768 : 65536; // frag-row stride

#pragma unroll
    for (int u = 0; u < 4; ++u)
      gll16(srcBase + (size_t)u * rowStr, ldsBase + u * 1024);
    asm volatile("s_waitcnt vmcnt(0)" ::: "memory");
    __builtin_amdgcn_s_barrier();

    const char* aB = (char*)smem + wr * 4096 + ln * 16;             // A frags wr*4+i
    const char* bB = (char*)smem + 8192 + wc * 4096 + ln * 16;      // B frags wc*4+j

#pragma unroll 1
    for (int kt = 0; kt < 32; ++kt) {
      const int cb = (kt & 1) << 15;
      const int nb = ((kt + 1) & 1) << 15;
      if (kt < 31) {
        const char* srcK = srcBase + (size_t)(kt + 1) * srcStep;
#pragma unroll
        for (int u = 0; u < 4; ++u)
          gll16(srcK + (size_t)u * rowStr, ldsBase + nb + u * 1024);
      }

      short8 bh[4];
#pragma unroll
      for (int j = 0; j < 4; ++j)
        bh[j] = *(const short8*)(bB + cb + j * 1024);
      __builtin_amdgcn_s_setprio(1);
#pragma unroll
      for (int i = 0; i < 4; ++i) {
        short8 ah = *(const short8*)(aB + cb + i * 1024);
#pragma unroll
        for (int j = 0; j < 4; ++j)
          acc[i][j] = __builtin_amdgcn_mfma_f32_16x16x32_bf16(ah, bh[j], acc[i][j], 0, 0, 0);
      }
      __builtin_amdgcn_s_setprio(0);

      asm volatile("s_waitcnt vmcnt(0)" ::: "memory");
      __builtin_amdgcn_s_barrier();
    }

#pragma unroll
    for (int i = 0; i < 4; ++i)
#pragma unroll
      for (int j = 0; j < 4; ++j) {
        int kv = n0 + wc * 64 + j * 16 + l16;
        int d = m0 + wr * 64 + i * 16 + quad * 4;
#pragma unroll
        for (int r2 = 0; r2 < 4; ++r2)
          Vt[pidx(d + r2, kv, NROWS / 32)] = f2bf(acc[i][j][r2]);
      }
  }
}

// ---------- S = Q*K^T (split): 256x256 tile, 8 waves, single-barrier LDS schedule ----
__global__ __launch_bounds__(512) void gemm_s(const ushort* __restrict__ Qc,
                                              const ushort* __restrict__ Kc,
                                              float* __restrict__ S) {
  __shared__ char smem[2][65536];
  const int bid = blockIdx.y * 16 + blockIdx.x;
  const int xcd = bid & 7, local = bid >> 3;   // 256 blocks = 1/CU
  const int m0 = ((xcd >> 1) * 4 + (local & 3)) * 256;
  const int n0 = ((xcd & 1) * 8 + (local >> 2)) * 256;
  const int t = threadIdx.x;
  const int w = t >> 6, ln = t & 63;
  const int wr = w >> 2, wc = w & 3;           // 2(M) x 4(N) wave grid
  const int quad = ln >> 4, l16 = ln & 15;

  const char* srcBase = (w < 4)
      ? (const char*)Qc + (size_t)((m0 >> 4) + w * 4) * 65536
      : (const char*)Kc + (size_t)((n0 >> 4) + (w - 4) * 4) * 65536;
  srcBase += ln * 16;
  char* ldsBase = (char*)smem + w * 8192 + ln * 16;

  f32x4 acc[8][4];
#pragma unroll
  for (int i = 0; i < 8; ++i)
#pragma unroll
    for (int j = 0; j < 4; ++j) acc[i][j] = (f32x4){0.f, 0.f, 0.f, 0.f};

#pragma unroll
  for (int u = 0; u < 8; ++u)
    gll16(srcBase + (u >> 1) * 65536 + (u & 1) * 1024, ldsBase + u * 1024);
  asm volatile("s_waitcnt vmcnt(0)" ::: "memory");
  __builtin_amdgcn_s_barrier();

  const char* aB = (char*)smem + (wr * 8) * 2048 + ln * 16;
  const char* bB = (char*)smem + 32768 + (wc * 4) * 2048 + ln * 16;

#pragma unroll 1
  for (int kt = 0; kt < 32; ++kt) {
    const int cb = (kt & 1) << 16;
    const int nb = ((kt + 1) & 1) << 16;
    const char* srcK = srcBase + (size_t)(kt + 1) * 2048;

    if (kt < 31) {
#pragma unroll
      for (int u = 0; u < 8; ++u)
        gll16(srcK + (u >> 1) * 65536 + (u & 1) * 1024, ldsBase + nb + u * 1024);
    }

    short8 bh[4], bl[4];
#pragma unroll
    for (int j = 0; j < 4; ++j) {
      bh[j] = *(const short8*)(bB + cb + j * 2048);
      bl[j] = *(const short8*)(bB + cb + j * 2048 + 1024);
    }

#pragma unroll
    for (int p = 0; p < 4; ++p) {
      short8 ah0 = *(const short8*)(aB + cb + (2 * p) * 2048);
      short8 al0 = *(const short8*)(aB + cb + (2 * p) * 2048 + 1024);
      short8 ah1 = *(const short8*)(aB + cb + (2 * p + 1) * 2048);
      short8 al1 = *(const short8*)(aB + cb + (2 * p + 1) * 2048 + 1024);
      __builtin_amdgcn_s_setprio(1);
#pragma unroll
      for (int j_ = 0; j_ < 4; ++j_) {
        acc[2 * p][j_] = __builtin_amdgcn_mfma_f32_16x16x32_bf16(ah0, bh[j_], acc[2 * p][j_], 0, 0, 0);
        acc[2 * p][j_] = __builtin_amdgcn_mfma_f32_16x16x32_bf16(ah0, bl[j_], acc[2 * p][j_], 0, 0, 0);
        acc[2 * p][j_] = __builtin_amdgcn_mfma_f32_16x16x32_bf16(al0, bh[j_], acc[2 * p][j_], 0, 0, 0);
        acc[2 * p + 1][j_] = __builtin_amdgcn_mfma_f32_16x16x32_bf16(ah1, bh[j_], acc[2 * p + 1][j_], 0, 0, 0);
        acc[2 * p + 1][j_] = __builtin_amdgcn_mfma_f32_16x16x32_bf16(ah1, bl[j_], acc[2 * p + 1][j_], 0, 0, 0);
        acc[2 * p + 1][j_] = __builtin_amdgcn_mfma_f32_16x16x32_bf16(al1, bh[j_], acc[2 * p + 1][j_], 0, 0, 0);
      }
      __builtin_amdgcn_s_setprio(0);
    }

    asm volatile("s_waitcnt vmcnt(0)" ::: "memory");
    __builtin_amdgcn_s_barrier();
  }

#pragma unroll
  for (int i = 0; i < 8; ++i)
#pragma unroll
    for (int j = 0; j < 4; ++j) {
      int col = n0 + wc * 64 + j * 16 + l16;
      int rw = m0 + wr * 128 + i * 16 + quad * 4;
#pragma unroll
      for (int r2 = 0; r2 < 4; ++r2)
        S[(size_t)(rw + r2) * NROWS + col] = acc[i][j][r2];
    }
}

// ---------- softmax: row of S (fp32) -> PACKED-16 bf16 P ----------
__global__ __launch_bounds__(256) void softmax_pack(const float* __restrict__ S,
                                                    ushort* __restrict__ P) {
  const int row = blockIdx.x, t = threadIdx.x;
  const float* Sr = S + (size_t)row * NROWS;
  const f32x4* S4 = (const f32x4*)Sr;
  f32x4 v[4];
  float mx = -3.4e38f;
#pragma unroll
  for (int c = 0; c < 4; ++c) {
    v[c] = S4[c * 256 + t];
    mx = fmaxf(mx, fmaxf(fmaxf(v[c].x, v[c].y), fmaxf(v[c].z, v[c].w)));
  }
  __shared__ float red[4];
  for (int o = 32; o >= 1; o >>= 1) mx = fmaxf(mx, __shfl_xor(mx, o));
  int wv = t >> 6, ln = t & 63;
  if (ln == 0) red[wv] = mx;
  __syncthreads();
  mx = fmaxf(fmaxf(red[0], red[1]), fmaxf(red[2], red[3]));
  float s = 0.f;
#pragma unroll
  for (int c = 0; c < 4; ++c) {
    v[c].x = __expf(v[c].x - mx);
    v[c].y = __expf(v[c].y - mx);
    v[c].z = __expf(v[c].z - mx);
    v[c].w = __expf(v[c].w - mx);
    s += v[c].x + v[c].y + v[c].z + v[c].w;
  }
  for (int o = 32; o >= 1; o >>= 1) s += __shfl_xor(s, o);
  __syncthreads();
  if (ln == 0) red[wv] = s;
  __syncthreads();
  s = red[0] + red[1] + red[2] + red[3];
  float inv = 1.f / s;
#pragma unroll
  for (int c = 0; c < 4; ++c) {
    ushort4 h;
    h.x = f2bf(v[c].x * inv);
    h.y = f2bf(v[c].y * inv);
    h.z = f2bf(v[c].z * inv);
    h.w = f2bf(v[c].w * inv);
    int c0 = 1024 * c + 4 * t;            // 4 consecutive cols, 8B-aligned in packed space
    *(ushort4*)(P + pidx(row, c0, NROWS / 32)) = h;
  }
}

// ---------- Out = P*V, LDS-free, barrier-free; BM=128 (r9 config) ----------
__global__ __launch_bounds__(256) void gemm_pv(const ushort* __restrict__ P,
                                               const ushort* __restrict__ Vt,
                                               float* __restrict__ Out) {
  const int n0 = blockIdx.x * 128, m0 = blockIdx.y * 128;
  const int t = threadIdx.x;
  const int wv = t >> 6, ln = t & 63;
  const int quad = ln >> 4, l16 = ln & 15;

  f32x4 acc[4][4];
#pragma unroll
  for (int i = 0; i < 4; ++i)
#pragma unroll
    for (int j = 0; j < 4; ++j) acc[i][j] = (f32x4){0.f, 0.f, 0.f, 0.f};

  direct_gemm<4, false, 128, 128, 512, 512>(P, Vt, m0, n0, acc);

#pragma unroll
  for (int i = 0; i < 4; ++i)
#pragma unroll
    for (int j = 0; j < 4; ++j) {
      int col = n0 + (wv & 1) * 64 + j * 16 + l16;
      int rw = m0 + (wv >> 1) * 64 + i * 16 + quad * 4;
#pragma unroll
      for (int r2 = 0; r2 < 4; ++r2)
        Out[(size_t)(rw + r2) * DDIM + col] = acc[i][j][r2];
    }
}

extern "C" void kernel_launch(void* const* d_in, const int* in_sizes, int n_in,
                              void* d_out, int out_size, void* d_ws, size_t ws_size,
                              hipStream_t stream) {
  const float* x  = (const float*)d_in[0];
  const float* wq = (const float*)d_in[1];
  const float* wk = (const float*)d_in[2];
  const float* wv = (const float*)d_in[3];
  char* ws = (char*)d_ws;
  const size_t MB = 1u << 20;

  // Workspace map (peak 104 MiB):
  ushort* Vt  = (ushort*)(ws + 0);        // 0-8    plain packed-16, alive through pv
  ushort* Qc  = (ushort*)(ws + 8 * MB);   // 8-24   split-16 Q (dead after gemm_s)
  ushort* Kc  = (ushort*)(ws + 24 * MB);  // 24-40  split-16 K (dead after gemm_s)
  ushort* Pp  = (ushort*)(ws + 8 * MB);   // 8-40   packed-16 P (aliases dead Q/K)
  ushort* Xc  = (ushort*)(ws + 40 * MB);  // 40-56  split-16 X (dead after qkv)
  ushort* Wqc = (ushort*)(ws + 56 * MB);  // 56-60  split-16 W^T (dead after qkv)
  ushort* Wkc = (ushort*)(ws + 60 * MB);  // 60-64
  ushort* Wvh = (ushort*)(ws + 64 * MB);  // 64-66  plain W_v^T
  float*  S   = (float*)(ws + 40 * MB);   // 40-104 fp32 S (overwrites dead X/W)
  float*  Out = (float*)d_out;

  prep<<<4096, 256, 0, stream>>>(x, wq, wk, wv, Xc, Wqc, Wkc, Wvh);
  gemm_qkv<<<768, 256, 0, stream>>>(Xc, Wqc, Wkc, Wvh, Qc, Kc, Vt);
  gemm_s<<<dim3(16, 16), 512, 0, stream>>>(Qc, Kc, S);
  softmax_pack<<<NROWS, 256, 0, stream>>>(S, Pp);
  gemm_pv<<<dim3(8, 32), 256, 0, stream>>>(Pp, Vt, Out);
}

// Round 16
// 284.110 us; speedup vs baseline: 1.1519x; 1.0579x over previous
//
#include <hip/hip_runtime.h>
#include <math.h>

#define NROWS 4096
#define DDIM  1024

typedef __attribute__((ext_vector_type(8))) short short8;
typedef __attribute__((ext_vector_type(4))) float f32x4;

// ---------- bf16 helpers (manual RNE) ----------
__device__ __forceinline__ ushort f2bf(float v) {
  union { float f; uint32_t u; } c; c.f = v;
  uint32_t u = c.u;
  uint32_t lsb = (u >> 16) & 1u;
  u += 0x7fffu + lsb;
  return (ushort)(u >> 16);
}
__device__ __forceinline__ float bf2f(ushort h) {
  union { uint32_t u; float f; } c; c.u = ((uint32_t)h) << 16;
  return c.f;
}

// ---------- async global->LDS, 16B per lane ----------
__device__ __forceinline__ void gll16(const void* g, void* l) {
  __builtin_amdgcn_global_load_lds((const __attribute__((address_space(1))) void*)g,
                                   (__attribute__((address_space(3))) void*)l, 16, 0, 0);
}

// ---------- packed-fragment layouts ----------
// PLAIN-16: [R][C] bf16 as 16x32 tiles of 1KB (512 ushorts). tile T=(r>>4)*ldt+(c>>5);
//   intra = ((c>>3)&3)*128 + (r&15)*8 + (c&7). Lane ln reads 16B at T*512+ln*8.
__device__ __forceinline__ size_t pidx(int r, int c, int ldt) {
  return ((size_t)((r >> 4) * ldt + (c >> 5))) * 512 +
         ((c >> 3) & 3) * 128 + (r & 15) * 8 + (c & 7);
}
// SPLIT-16: hi fragment then its lo fragment (tile = 1024 ushorts; lo at +512).
__device__ __forceinline__ size_t pidxs(int r, int c, int ldt) {
  return ((size_t)((r >> 4) * ldt + (c >> 5))) * 1024 +
         ((c >> 3) & 3) * 128 + (r & 15) * 8 + (c & 7);
}
// P layout (row-panel): offset(r,c) = (c>>5)*131072 + r*32 + (c&31) ushorts.
// A-fragment (rows base..base+15, k-tile kt) is 1KB contiguous at
// kt*131072 + fragrow*512; lane ln reads 16B at +(ln&15)*32 + (ln>>4)*8.

// ---------- prep: split x + transpose/split 3 weights; LDS-staged coalesced stores ----
// blocks 0-511: x (16 tiles each, 4 waves x 4 iters). blocks 512-3583: W tiles.
__global__ __launch_bounds__(256) void prep(const float* __restrict__ x,
                                            const float* __restrict__ wq,
                                            const float* __restrict__ wk,
                                            const float* __restrict__ wv,
                                            ushort* Xc,
                                            ushort* Wqc, ushort* Wkc, ushort* Wvh) {
  __shared__ char smem[8448];
  const int b = blockIdx.x, t = threadIdx.x;
  if (b < 512) {
    // ---- x split: 8192 tiles of 16x32; per-wave LDS tile image [hi 1KB][lo 1KB] ----
    ushort* xb = (ushort*)smem;                 // 4 waves x 1024 ushorts (2KB each)
    const int w = t >> 6, l = t & 63;
    ushort* wb = xb + w * 1024;
#pragma unroll 1
    for (int it = 0; it < 4; ++it) {
      int tile = b * 16 + it * 4 + w;           // 0..8191; == packed tile index
      int tr = tile >> 5, tc = tile & 31;
      const float* src = x + (size_t)(tr * 16) * DDIM + tc * 32;
      int r = l >> 3, cq = l & 7;
#pragma unroll
      for (int hh = 0; hh < 2; ++hh) {
        int rr = r + 8 * hh;
        f32x4 v = __builtin_nontemporal_load(
            (const f32x4*)(src + (size_t)rr * DDIM) + cq);
        int c = cq * 4;
        int intra = ((c >> 3) & 3) * 128 + rr * 8 + (c & 7);
        ushort4 hi, lo;
        hi.x = f2bf(v.x); lo.x = f2bf(v.x - bf2f(hi.x));
        hi.y = f2bf(v.y); lo.y = f2bf(v.y - bf2f(hi.y));
        hi.z = f2bf(v.z); lo.z = f2bf(v.z - bf2f(hi.z));
        hi.w = f2bf(v.w); lo.w = f2bf(v.w - bf2f(hi.w));
        *(ushort4*)(wb + intra) = hi;
        *(ushort4*)(wb + 512 + intra) = lo;
      }
      __syncthreads();
      ushort* dst = Xc + (size_t)tile * 1024;
#pragma unroll
      for (int rd = 0; rd < 2; ++rd)
        *(short8*)(dst + rd * 512 + l * 8) = *(const short8*)(wb + rd * 512 + l * 8);
      __syncthreads();
    }
  } else {
    // ---- W transpose+split: LDS transpose, stage packed tiles, coalesced copy ----
    float (*tl)[33] = (float(*)[33])smem;       // 4224 B
    ushort* stg = (ushort*)(smem + 4224);       // up to 2048 ushorts (4KB)
    const int z = (b - 512) >> 10;
    const int tile = (b - 512) & 1023;
    const float* src = z == 0 ? wq : (z == 1 ? wk : wv);
    const int r0 = (tile >> 5) * 32;            // W row  = W^T col
    const int c0 = (tile & 31) * 32;            // W col  = W^T row
    const int tx = t & 31, ty = t >> 5;
    for (int i = ty; i < 32; i += 8)
      tl[i][tx] = __builtin_nontemporal_load(&src[(size_t)(r0 + i) * DDIM + c0 + tx]);
    __syncthreads();
    // element: W^T[c0+i][r0+tx] = tl[tx][i]; intra uses r&15=i&15, c-part from tx.
    const size_t T0 = (size_t)(c0 >> 4) * 32 + (r0 >> 5);   // first packed tile; second at +32
    if (z == 2) {
      for (int i = ty; i < 32; i += 8) {
        int intra = ((tx >> 3) & 3) * 128 + (i & 15) * 8 + (tx & 7);
        stg[(i >> 4) * 512 + intra] = f2bf(tl[tx][i]);
      }
      __syncthreads();
      int s = t >> 7, idx = (t & 127) * 4;
      *(ushort4*)(Wvh + (T0 + (size_t)s * 32) * 512 + idx) = *(const ushort4*)(stg + s * 512 + idx);
    } else {
      ushort* D = z == 0 ? Wqc : Wkc;
      for (int i = ty; i < 32; i += 8) {
        float v = tl[tx][i];
        ushort h = f2bf(v);
        int intra = ((tx >> 3) & 3) * 128 + (i & 15) * 8 + (tx & 7);
        stg[(i >> 4) * 1024 + intra] = h;
        stg[(i >> 4) * 1024 + 512 + intra] = f2bf(v - bf2f(h));
      }
      __syncthreads();
      int s = t >> 7, idx = (t & 127) * 8;
      *(ushort4*)(D + (T0 + (size_t)s * 32) * 1024 + idx) = *(const ushort4*)(stg + s * 1024 + idx);
      *(ushort4*)(D + (T0 + (size_t)s * 32) * 1024 + idx + 4) = *(const ushort4*)(stg + s * 1024 + idx + 4);
    }
  }
}

// ---------- fused QKV: 128x128-tile LDS single-barrier schedule, 768 blocks ----------
// V blocks dispatch FIRST (256, work 1), then Q (256) and K (256) at work 3:
// V blocks spread across CUs early instead of forming a low-occupancy tail.
__global__ __launch_bounds__(256) void gemm_qkv(const ushort* __restrict__ Xc,
                                                const ushort* __restrict__ Wqc,
                                                const ushort* __restrict__ Wkc,
                                                const ushort* __restrict__ Wvh,
                                                ushort* Qc, ushort* Kc, ushort* Vt) {
  __shared__ char smem[2][32768];
  const int bid = blockIdx.x;
  const int which = bid < 256 ? 2 : (bid < 512 ? 0 : 1);   // V, Q, K
  const int local = bid & 255;
  const int xcd = local & 7, idx = local >> 3;
  const int t = threadIdx.x;
  const int w = t >> 6, ln = t & 63;
  const int wr = w >> 1, wc = w & 1;         // 2x2 wave grid, 64x64 each
  const int quad = ln >> 4, l16 = ln & 15;

  f32x4 acc[4][4];
#pragma unroll
  for (int i = 0; i < 4; ++i)
#pragma unroll
    for (int j = 0; j < 4; ++j) acc[i][j] = (f32x4){0.f, 0.f, 0.f, 0.f};

  if (which < 2) {
    // ---- Q/K: [m0..+127][n0..+127] = X(split) . W^T(split), K=1024 ----
    const int m0 = (xcd * 4 + (idx >> 3)) * 128;   // rows over 4096
    const int n0 = (idx & 7) * 128;                // d over 1024
    const ushort* Bc = which ? Wkc : Wqc;
    const char* srcBase = (w < 2)
        ? (const char*)Xc + (size_t)((m0 >> 4) + (w & 1) * 4) * 65536
        : (const char*)Bc + (size_t)((n0 >> 4) + (w & 1) * 4) * 65536;
    srcBase += ln * 16;
    char* ldsBase = (char*)smem + (w < 2 ? 0 : 16384) + (w & 1) * 8192 + ln * 16;

#pragma unroll
    for (int u = 0; u < 8; ++u)
      gll16(srcBase + (u >> 1) * 65536 + (u & 1) * 1024, ldsBase + u * 1024);
    asm volatile("s_waitcnt vmcnt(0)" ::: "memory");
    __builtin_amdgcn_s_barrier();

    const char* aB = (char*)smem + wr * 8192 + ln * 16;
    const char* bB = (char*)smem + 16384 + wc * 8192 + ln * 16;

#pragma unroll 1
    for (int kt = 0; kt < 32; ++kt) {
      const int cb = (kt & 1) << 15;
      const int nb = ((kt + 1) & 1) << 15;
      if (kt < 31) {
        const char* srcK = srcBase + (size_t)(kt + 1) * 2048;
#pragma unroll
        for (int u = 0; u < 8; ++u)
          gll16(srcK + (u >> 1) * 65536 + (u & 1) * 1024, ldsBase + nb + u * 1024);
      }

      short8 bh[4], bl[4];
#pragma unroll
      for (int j = 0; j < 4; ++j) {
        bh[j] = *(const short8*)(bB + cb + j * 2048);
        bl[j] = *(const short8*)(bB + cb + j * 2048 + 1024);
      }
      __builtin_amdgcn_s_setprio(1);
#pragma unroll
      for (int i = 0; i < 4; ++i) {
        short8 ah = *(const short8*)(aB + cb + i * 2048);
        short8 al = *(const short8*)(aB + cb + i * 2048 + 1024);
#pragma unroll
        for (int j = 0; j < 4; ++j) {
          acc[i][j] = __builtin_amdgcn_mfma_f32_16x16x32_bf16(ah, bh[j], acc[i][j], 0, 0, 0);
          acc[i][j] = __builtin_amdgcn_mfma_f32_16x16x32_bf16(ah, bl[j], acc[i][j], 0, 0, 0);
          acc[i][j] = __builtin_amdgcn_mfma_f32_16x16x32_bf16(al, bh[j], acc[i][j], 0, 0, 0);
        }
      }
      __builtin_amdgcn_s_setprio(0);

      asm volatile("s_waitcnt vmcnt(0)" ::: "memory");
      __builtin_amdgcn_s_barrier();
    }

    const float scale = which ? 1.0f : 0.03125f;   // fold 1/sqrt(1024) into Q
    ushort* D = which ? Kc : Qc;
#pragma unroll
    for (int i = 0; i < 4; ++i)
#pragma unroll
      for (int j = 0; j < 4; ++j) {
        int col = n0 + wc * 64 + j * 16 + l16;
        int rw = m0 + wr * 64 + i * 16 + quad * 4;
#pragma unroll
        for (int r2 = 0; r2 < 4; ++r2) {
          float v = acc[i][j][r2] * scale;
          ushort h = f2bf(v);
          size_t o = pidxs(rw + r2, col, DDIM / 32);
          D[o] = h;
          D[o + 512] = f2bf(v - bf2f(h));
        }
      }
  } else {
    // ---- V: Vt[d][kv] = WvT(plain) . X(hi only), K=1024 ----
    const int m0 = (idx & 7) * 128;                // d over 1024
    const int n0 = (xcd * 4 + (idx >> 3)) * 128;   // kv over 4096
    const char* srcBase = (w < 2)
        ? (const char*)Wvh + (size_t)((m0 >> 4) + (w & 1) * 4) * 32768
        : (const char*)Xc + (size_t)((n0 >> 4) + (w & 1) * 4) * 65536;
    srcBase += ln * 16;
    char* ldsBase = (char*)smem + (w < 2 ? 0 : 8192) + (w & 1) * 4096 + ln * 16;
    const size_t srcStep = (w < 2) ? 1024 : 2048;
    const size_t rowStr = (w < 2) ? 32768 : 65536;

#pragma unroll
    for (int u = 0; u < 4; ++u)
      gll16(srcBase + (size_t)u * rowStr, ldsBase + u * 1024);
    asm volatile("s_waitcnt vmcnt(0)" ::: "memory");
    __builtin_amdgcn_s_barrier();

    const char* aB = (char*)smem + wr * 4096 + ln * 16;
    const char* bB = (char*)smem + 8192 + wc * 4096 + ln * 16;

#pragma unroll 1
    for (int kt = 0; kt < 32; ++kt) {
      const int cb = (kt & 1) << 15;
      const int nb = ((kt + 1) & 1) << 15;
      if (kt < 31) {
        const char* srcK = srcBase + (size_t)(kt + 1) * srcStep;
#pragma unroll
        for (int u = 0; u < 4; ++u)
          gll16(srcK + (size_t)u * rowStr, ldsBase + nb + u * 1024);
      }

      short8 bh[4];
#pragma unroll
      for (int j = 0; j < 4; ++j)
        bh[j] = *(const short8*)(bB + cb + j * 1024);
      __builtin_amdgcn_s_setprio(1);
#pragma unroll
      for (int i = 0; i < 4; ++i) {
        short8 ah = *(const short8*)(aB + cb + i * 1024);
#pragma unroll
        for (int j = 0; j < 4; ++j)
          acc[i][j] = __builtin_amdgcn_mfma_f32_16x16x32_bf16(ah, bh[j], acc[i][j], 0, 0, 0);
      }
      __builtin_amdgcn_s_setprio(0);

      asm volatile("s_waitcnt vmcnt(0)" ::: "memory");
      __builtin_amdgcn_s_barrier();
    }

#pragma unroll
    for (int i = 0; i < 4; ++i)
#pragma unroll
      for (int j = 0; j < 4; ++j) {
        int kv = n0 + wc * 64 + j * 16 + l16;
        int d = m0 + wr * 64 + i * 16 + quad * 4;
#pragma unroll
        for (int r2 = 0; r2 < 4; ++r2)
          Vt[pidx(d + r2, kv, NROWS / 32)] = f2bf(acc[i][j][r2]);
      }
  }
}

// ---------- S = Q*K^T (split): 256x256 tile, 8 waves, single-barrier LDS schedule ----
__global__ __launch_bounds__(512) void gemm_s(const ushort* __restrict__ Qc,
                                              const ushort* __restrict__ Kc,
                                              float* __restrict__ S) {
  __shared__ char smem[2][65536];
  const int bid = blockIdx.y * 16 + blockIdx.x;
  const int xcd = bid & 7, local = bid >> 3;   // 256 blocks = 1/CU
  const int m0 = ((xcd >> 1) * 4 + (local & 3)) * 256;
  const int n0 = ((xcd & 1) * 8 + (local >> 2)) * 256;
  const int t = threadIdx.x;
  const int w = t >> 6, ln = t & 63;
  const int wr = w >> 2, wc = w & 3;           // 2(M) x 4(N) wave grid
  const int quad = ln >> 4, l16 = ln & 15;

  const char* srcBase = (w < 4)
      ? (const char*)Qc + (size_t)((m0 >> 4) + w * 4) * 65536
      : (const char*)Kc + (size_t)((n0 >> 4) + (w - 4) * 4) * 65536;
  srcBase += ln * 16;
  char* ldsBase = (char*)smem + w * 8192 + ln * 16;

  f32x4 acc[8][4];
#pragma unroll
  for (int i = 0; i < 8; ++i)
#pragma unroll
    for (int j = 0; j < 4; ++j) acc[i][j] = (f32x4){0.f, 0.f, 0.f, 0.f};

#pragma unroll
  for (int u = 0; u < 8; ++u)
    gll16(srcBase + (u >> 1) * 65536 + (u & 1) * 1024, ldsBase + u * 1024);
  asm volatile("s_waitcnt vmcnt(0)" ::: "memory");
  __builtin_amdgcn_s_barrier();

  const char* aB = (char*)smem + (wr * 8) * 2048 + ln * 16;
  const char* bB = (char*)smem + 32768 + (wc * 4) * 2048 + ln * 16;

#pragma unroll 1
  for (int kt = 0; kt < 32; ++kt) {
    const int cb = (kt & 1) << 16;
    const int nb = ((kt + 1) & 1) << 16;
    const char* srcK = srcBase + (size_t)(kt + 1) * 2048;

    if (kt < 31) {
#pragma unroll
      for (int u = 0; u < 8; ++u)
        gll16(srcK + (u >> 1) * 65536 + (u & 1) * 1024, ldsBase + nb + u * 1024);
    }

    short8 bh[4], bl[4];
#pragma unroll
    for (int j = 0; j < 4; ++j) {
      bh[j] = *(const short8*)(bB + cb + j * 2048);
      bl[j] = *(const short8*)(bB + cb + j * 2048 + 1024);
    }

#pragma unroll
    for (int p = 0; p < 4; ++p) {
      short8 ah0 = *(const short8*)(aB + cb + (2 * p) * 2048);
      short8 al0 = *(const short8*)(aB + cb + (2 * p) * 2048 + 1024);
      short8 ah1 = *(const short8*)(aB + cb + (2 * p + 1) * 2048);
      short8 al1 = *(const short8*)(aB + cb + (2 * p + 1) * 2048 + 1024);
      __builtin_amdgcn_s_setprio(1);
#pragma unroll
      for (int j_ = 0; j_ < 4; ++j_) {
        acc[2 * p][j_] = __builtin_amdgcn_mfma_f32_16x16x32_bf16(ah0, bh[j_], acc[2 * p][j_], 0, 0, 0);
        acc[2 * p][j_] = __builtin_amdgcn_mfma_f32_16x16x32_bf16(ah0, bl[j_], acc[2 * p][j_], 0, 0, 0);
        acc[2 * p][j_] = __builtin_amdgcn_mfma_f32_16x16x32_bf16(al0, bh[j_], acc[2 * p][j_], 0, 0, 0);
        acc[2 * p + 1][j_] = __builtin_amdgcn_mfma_f32_16x16x32_bf16(ah1, bh[j_], acc[2 * p + 1][j_], 0, 0, 0);
        acc[2 * p + 1][j_] = __builtin_amdgcn_mfma_f32_16x16x32_bf16(ah1, bl[j_], acc[2 * p + 1][j_], 0, 0, 0);
        acc[2 * p + 1][j_] = __builtin_amdgcn_mfma_f32_16x16x32_bf16(al1, bh[j_], acc[2 * p + 1][j_], 0, 0, 0);
      }
      __builtin_amdgcn_s_setprio(0);
    }

    asm volatile("s_waitcnt vmcnt(0)" ::: "memory");
    __builtin_amdgcn_s_barrier();
  }

#pragma unroll
  for (int i = 0; i < 8; ++i)
#pragma unroll
    for (int j = 0; j < 4; ++j) {
      int col = n0 + wc * 64 + j * 16 + l16;
      int rw = m0 + wr * 128 + i * 16 + quad * 4;
#pragma unroll
      for (int r2 = 0; r2 < 4; ++r2)
        S[(size_t)(rw + r2) * NROWS + col] = acc[i][j][r2];
    }
}

// ---------- softmax: row of S (fp32) -> P row-panel layout (coalesced 64B runs) ----
__global__ __launch_bounds__(256) void softmax_pack(const float* __restrict__ S,
                                                    ushort* __restrict__ P) {
  const int row = blockIdx.x, t = threadIdx.x;
  const float* Sr = S + (size_t)row * NROWS;
  const f32x4* S4 = (const f32x4*)Sr;
  f32x4 v[4];
  float mx = -3.4e38f;
#pragma unroll
  for (int c = 0; c < 4; ++c) {
    v[c] = S4[c * 256 + t];
    mx = fmaxf(mx, fmaxf(fmaxf(v[c].x, v[c].y), fmaxf(v[c].z, v[c].w)));
  }
  __shared__ float red[4];
  for (int o = 32; o >= 1; o >>= 1) mx = fmaxf(mx, __shfl_xor(mx, o));
  int wv = t >> 6, ln = t & 63;
  if (ln == 0) red[wv] = mx;
  __syncthreads();
  mx = fmaxf(fmaxf(red[0], red[1]), fmaxf(red[2], red[3]));
  float s = 0.f;
#pragma unroll
  for (int c = 0; c < 4; ++c) {
    v[c].x = __expf(v[c].x - mx);
    v[c].y = __expf(v[c].y - mx);
    v[c].z = __expf(v[c].z - mx);
    v[c].w = __expf(v[c].w - mx);
    s += v[c].x + v[c].y + v[c].z + v[c].w;
  }
  for (int o = 32; o >= 1; o >>= 1) s += __shfl_xor(s, o);
  __syncthreads();
  if (ln == 0) red[wv] = s;
  __syncthreads();
  s = red[0] + red[1] + red[2] + red[3];
  float inv = 1.f / s;
#pragma unroll
  for (int c = 0; c < 4; ++c) {
    ushort4 h;
    h.x = f2bf(v[c].x * inv);
    h.y = f2bf(v[c].y * inv);
    h.z = f2bf(v[c].z * inv);
    h.w = f2bf(v[c].w * inv);
    int kt = 32 * c + (t >> 3);               // k-tile of cols 1024c+4t..+3
    *(ushort4*)(P + (size_t)kt * 131072 + (size_t)row * 32 + 4 * (t & 7)) = h;
  }
}

// ---------- Out = P*V, LDS-free, barrier-free; BM=128; P row-panel A-operand ----
__global__ __launch_bounds__(256) void gemm_pv(const ushort* __restrict__ P,
                                               const ushort* __restrict__ Vt,
                                               float* __restrict__ Out) {
  const int n0 = blockIdx.x * 128, m0 = blockIdx.y * 128;
  const int t = threadIdx.x;
  const int wv = t >> 6, ln = t & 63;
  const int quad = ln >> 4, l16 = ln & 15;
  const int arb = (wv >> 1) * 64, crb = (wv & 1) * 64;
  const int ra = (m0 + arb) >> 4;
  const int rb = (n0 + crb) >> 4;

  f32x4 acc[4][4];
#pragma unroll
  for (int i = 0; i < 4; ++i)
#pragma unroll
    for (int j = 0; j < 4; ++j) acc[i][j] = (f32x4){0.f, 0.f, 0.f, 0.f};

  uint oA[4], oB[4];
#pragma unroll
  for (int i = 0; i < 4; ++i)
    oA[i] = (uint)(ra + i) * 512u + (uint)(ln & 15) * 32u + (uint)(ln >> 4) * 8u;
#pragma unroll
  for (int j = 0; j < 4; ++j)
    oB[j] = (uint)(rb + j) * 65536u + (uint)ln * 8u;

  short8 a0[4], b0[4], a1[4], b1[4];

#define PV_LOAD(sidx, AH, BH)                                                \
  {                                                                          \
    uint ka_ = (uint)(sidx)*131072u;                                         \
    uint kb_ = (uint)(sidx)*512u;                                            \
    _Pragma("unroll") for (int i_ = 0; i_ < 4; ++i_)                         \
      AH[i_] = *(const short8*)(P + oA[i_] + ka_);                           \
    _Pragma("unroll") for (int j_ = 0; j_ < 4; ++j_)                         \
      BH[j_] = *(const short8*)(Vt + oB[j_] + kb_);                          \
  }

#define PV_MFMA(AH, BH)                                                      \
  {                                                                          \
    __builtin_amdgcn_s_setprio(1);                                           \
    _Pragma("unroll") for (int j_ = 0; j_ < 4; ++j_)                         \
      _Pragma("unroll") for (int i_ = 0; i_ < 4; ++i_)                       \
        acc[i_][j_] = __builtin_amdgcn_mfma_f32_16x16x32_bf16(               \
            AH[i_], BH[j_], acc[i_][j_], 0, 0, 0);                           \
    __builtin_amdgcn_s_setprio(0);                                           \
  }

  PV_LOAD(0, a0, b0);
#pragma unroll 1
  for (int s = 0; s < 126; s += 2) {
    PV_LOAD(s + 1, a1, b1);
    PV_MFMA(a0, b0);
    PV_LOAD(s + 2, a0, b0);
    PV_MFMA(a1, b1);
  }
  PV_LOAD(127, a1, b1);
  PV_MFMA(a0, b0);
  PV_MFMA(a1, b1);
#undef PV_LOAD
#undef PV_MFMA

#pragma unroll
  for (int i = 0; i < 4; ++i)
#pragma unroll
    for (int j = 0; j < 4; ++j) {
      int col = n0 + crb + j * 16 + l16;
      int rw = m0 + arb + i * 16 + quad * 4;
#pragma unroll
      for (int r2 = 0; r2 < 4; ++r2)
        Out[(size_t)(rw + r2) * DDIM + col] = acc[i][j][r2];
    }
}

extern "C" void kernel_launch(void* const* d_in, const int* in_sizes, int n_in,
                              void* d_out, int out_size, void* d_ws, size_t ws_size,
                              hipStream_t stream) {
  const float* x  = (const float*)d_in[0];
  const float* wq = (const float*)d_in[1];
  const float* wk = (const float*)d_in[2];
  const float* wv = (const float*)d_in[3];
  char* ws = (char*)d_ws;
  const size_t MB = 1u << 20;

  // Workspace map (peak 104 MiB):
  ushort* Vt  = (ushort*)(ws + 0);        // 0-8    plain packed-16, alive through pv
  ushort* Qc  = (ushort*)(ws + 8 * MB);   // 8-24   split-16 Q (dead after gemm_s)
  ushort* Kc  = (ushort*)(ws + 24 * MB);  // 24-40  split-16 K (dead after gemm_s)
  ushort* Pp  = (ushort*)(ws + 8 * MB);   // 8-40   row-panel P (aliases dead Q/K)
  ushort* Xc  = (ushort*)(ws + 40 * MB);  // 40-56  split-16 X (dead after qkv)
  ushort* Wqc = (ushort*)(ws + 56 * MB);  // 56-60  split-16 W^T (dead after qkv)
  ushort* Wkc = (ushort*)(ws + 60 * MB);  // 60-64
  ushort* Wvh = (ushort*)(ws + 64 * MB);  // 64-66  plain W_v^T
  float*  S   = (float*)(ws + 40 * MB);   // 40-104 fp32 S (overwrites dead X/W)
  float*  Out = (float*)d_out;

  prep<<<3584, 256, 0, stream>>>(x, wq, wk, wv, Xc, Wqc, Wkc, Wvh);
  gemm_qkv<<<768, 256, 0, stream>>>(Xc, Wqc, Wkc, Wvh, Qc, Kc, Vt);
  gemm_s<<<dim3(16, 16), 512, 0, stream>>>(Qc, Kc, S);
  softmax_pack<<<NROWS, 256, 0, stream>>>(S, Pp);
  gemm_pv<<<dim3(8, 32), 256, 0, stream>>>(Pp, Vt, Out);
}